// Round 15
// baseline (486.135 us; speedup 1.0000x reference)
//
#include <hip/hip_runtime.h>
#include <hip/hip_bf16.h>

typedef __hip_bfloat16 bf16;
typedef __attribute__((ext_vector_type(8))) short short8;
typedef __attribute__((ext_vector_type(4))) float f32x4;

#define D_MODELC 1024
#define D_FFC    4096
#define NHEADS   16
#define HDIM     64
#define SEQLEN   2048
#define BATCHN   4
#define MTOT     (BATCHN * SEQLEN)   // 8192

// ---------------- async global->LDS (16B per lane) ----------------
__device__ __forceinline__ void async16(void* lds, const void* g) {
  __builtin_amdgcn_global_load_lds(
      (const __attribute__((address_space(1))) unsigned int*)g,
      (__attribute__((address_space(3))) unsigned int*)lds, 16, 0, 0);
}

// ---------------- weight transpose-convert: src[R][C] f32 -> dst[C][R] bf16 * scale ----------------
__global__ __launch_bounds__(256) void transpose_bf16_k(
    const float* __restrict__ src, bf16* __restrict__ dst, int R, int C, float scale) {
  __shared__ float tile[32][33];
  int tx = threadIdx.x & 31, ty = threadIdx.x >> 5;  // ty: 0..7
  int r0 = blockIdx.y * 32, c0 = blockIdx.x * 32;
#pragma unroll
  for (int i = 0; i < 4; i++) {
    int r = ty + i * 8;
    tile[r][tx] = src[(size_t)(r0 + r) * C + c0 + tx];
  }
  __syncthreads();
#pragma unroll
  for (int i = 0; i < 4; i++) {
    int c = ty + i * 8;
    dst[(size_t)(c0 + c) * R + r0 + tx] = __float2bfloat16(tile[tx][c] * scale);
  }
}

// ---------------- LayerNorm f32 row (1024) -> bf16 ----------------
__global__ __launch_bounds__(256) void ln_bf16_k(
    const float* __restrict__ x, const float* __restrict__ g,
    const float* __restrict__ b, bf16* __restrict__ out) {
  int row = blockIdx.x;
  int t = threadIdx.x;
  f32x4 v = ((const f32x4*)(x + (size_t)row * D_MODELC))[t];
  float s = v[0] + v[1] + v[2] + v[3];
  float ss = v[0] * v[0] + v[1] * v[1] + v[2] * v[2] + v[3] * v[3];
#pragma unroll
  for (int m = 1; m < 64; m <<= 1) {
    s += __shfl_xor(s, m);
    ss += __shfl_xor(ss, m);
  }
  __shared__ float red[8];
  int w = t >> 6, l = t & 63;
  if (l == 0) { red[w] = s; red[4 + w] = ss; }
  __syncthreads();
  s = red[0] + red[1] + red[2] + red[3];
  ss = red[4] + red[5] + red[6] + red[7];
  float mean = s * (1.0f / D_MODELC);
  float var = ss * (1.0f / D_MODELC) - mean * mean;
  float rs = rsqrtf(var + 1e-5f);
  f32x4 gv = ((const f32x4*)g)[t];
  f32x4 bv = ((const f32x4*)b)[t];
  unsigned short u[4];
#pragma unroll
  for (int j = 0; j < 4; j++) {
    float o = (v[j] - mean) * rs * gv[j] + bv[j];
    u[j] = __bfloat16_as_ushort(__float2bfloat16(o));
  }
  unsigned int lo = (unsigned int)u[0] | ((unsigned int)u[1] << 16);
  unsigned int hi = (unsigned int)u[2] | ((unsigned int)u[3] << 16);
  ((uint2*)(out + (size_t)row * D_MODELC))[t] = make_uint2(lo, hi);
}

enum { EPI_QKV = 0, EPI_RESID = 1, EPI_BIAS_RELU = 2, EPI_BIAS_RESID = 3 };

// ---------------- epilogue element write ----------------
template <int EPI>
__device__ __forceinline__ void epi_write(
    int gm, int gn, float v, int N,
    const float* __restrict__ bias, const float* __restrict__ resid,
    float* __restrict__ outF, bf16* __restrict__ outB) {
  if constexpr (EPI == EPI_QKV) {
    int sel = gn >> 10, d = gn & 1023;
    int b_ = gm >> 11, s_ = gm & 2047;
    int h2 = d >> 6, dd = d & 63;
    size_t bh = (size_t)b_ * NHEADS + h2;
    size_t dst;
    if (sel < 2) {
      dst = (size_t)sel * ((size_t)MTOT * D_MODELC) + (bh * SEQLEN + s_) * HDIM + dd;
    } else {
      // V stored TRANSPOSED: [bh][d][S]
      dst = 2 * ((size_t)MTOT * D_MODELC) + (bh * HDIM + dd) * SEQLEN + s_;
    }
    outB[dst] = __float2bfloat16(v);
  } else if constexpr (EPI == EPI_RESID) {
    size_t idx = (size_t)gm * N + gn;
    outF[idx] = resid[idx] + v;
  } else if constexpr (EPI == EPI_BIAS_RELU) {
    float z = v + bias[gn];
    outB[(size_t)gm * N + gn] = __float2bfloat16(z > 0.f ? z : 0.f);
  } else {
    size_t idx = (size_t)gm * N + gn;
    outF[idx] = resid[idx] + v + bias[gn];
  }
}

// ---------------- 128x128 bf16 NT GEMM (proven m97-structure) ----------------
#define BM 128
#define BN 128
#define BKK 64

template <int EPI>
__global__ __launch_bounds__(256) void gemm_nt(
    const bf16* __restrict__ A, const bf16* __restrict__ BT, int M, int N, int K,
    const float* __restrict__ bias, const float* __restrict__ resid,
    float* __restrict__ outF, bf16* __restrict__ outB) {
  __shared__ bf16 As[BM * BKK];
  __shared__ bf16 Bs[BN * BKK];
  const int t = threadIdx.x;
  const int l = t & 63;
  const int w = t >> 6;
  const int wm = w >> 1, wn = w & 1;

  int nwg = gridDim.x * gridDim.y;
  int bid = blockIdx.y * gridDim.x + blockIdx.x;
  if ((nwg & 7) == 0) {
    int q8 = nwg >> 3;
    bid = (bid & 7) * q8 + (bid >> 3);
  }
  const int bx = bid % gridDim.x, by = bid / gridDim.x;
  const int m0 = by * BM, n0 = bx * BN;
  const int lr = l & 15, lkg = l >> 4;

  f32x4 acc[4][4];
#pragma unroll
  for (int i = 0; i < 4; i++)
#pragma unroll
    for (int j = 0; j < 4; j++) acc[i][j] = (f32x4){0.f, 0.f, 0.f, 0.f};

  const char* Abase = (const char*)(A + (size_t)m0 * K);
  const char* Bbase = (const char*)(BT + (size_t)n0 * K);

  for (int k0 = 0; k0 < K; k0 += BKK) {
#pragma unroll
    for (int c = 0; c < 4; c++) {
      int off = (c * 256 + t) * 16;
      int r = off >> 7;
      int sg = ((off >> 4) & 7) ^ (r & 7);
      async16((char*)As + off, Abase + ((size_t)r * K + k0) * 2 + sg * 16);
      async16((char*)Bs + off, Bbase + ((size_t)r * K + k0) * 2 + sg * 16);
    }
    __syncthreads();
    short8 a[2][4], b[2][4];
#pragma unroll
    for (int kk = 0; kk < 2; kk++) {
#pragma unroll
      for (int mi = 0; mi < 4; mi++) {
        int row = wm * 64 + mi * 16 + lr;
        int sl = (kk * 4 + lkg) ^ (row & 7);
        a[kk][mi] = *(const short8*)((const char*)As + row * 128 + sl * 16);
      }
#pragma unroll
      for (int ni = 0; ni < 4; ni++) {
        int row = wn * 64 + ni * 16 + lr;
        int sl = (kk * 4 + lkg) ^ (row & 7);
        b[kk][ni] = *(const short8*)((const char*)Bs + row * 128 + sl * 16);
      }
    }
#pragma unroll
    for (int kk = 0; kk < 2; kk++)
#pragma unroll
      for (int mi = 0; mi < 4; mi++)
#pragma unroll
        for (int ni = 0; ni < 4; ni++)
          acc[mi][ni] = __builtin_amdgcn_mfma_f32_16x16x32_bf16(a[kk][mi], b[kk][ni], acc[mi][ni], 0, 0, 0);
    __syncthreads();
  }

#pragma unroll
  for (int mi = 0; mi < 4; mi++)
#pragma unroll
    for (int ni = 0; ni < 4; ni++)
#pragma unroll
      for (int j = 0; j < 4; j++) {
        int gm = m0 + wm * 64 + mi * 16 + lkg * 4 + j;
        int gn = n0 + wn * 64 + ni * 16 + lr;
        epi_write<EPI>(gm, gn, acc[mi][ni][j], N, bias, resid, outF, outB);
      }
}

// ---------------- 256x256 8-phase GEMM, K-half staging (corrected m201 port) ----------------
// 512 thr = 8 waves (2M x 4N), per-wave 128x64 out. BK=64 split into two K-halves
// of 32 cols; LDS [buf][kh][256 rows][32] (16KB planes, linear-stageable).
// Phase p of tile kt: (kh=p>>1, mih=p&1): 8 ds_read_b128 + 1 half-stage of tile
// kt+1 into the DEAD buffer + 16 MFMA. First use of kh1 is phase 2 => counted
// vmcnt(4) needed only at phases 1 and 3 (never 0 in the loop).
#define G8M 256
#define G8N 256
#define G8K 64

template <int EPI>
__global__ __launch_bounds__(512) void gemm8p(
    const bf16* __restrict__ A, const bf16* __restrict__ BT, int N, int K,
    const float* __restrict__ bias, const float* __restrict__ resid,
    float* __restrict__ outF, bf16* __restrict__ outB) {
  __shared__ bf16 As[2][2][G8M * 32];   // 64KB
  __shared__ bf16 Bs[2][2][G8N * 32];   // 64KB
  const int t = threadIdx.x;
  const int l = t & 63, wid = t >> 6;
  const int wr = wid >> 2, wc = wid & 3;
  const int lr = l & 15, lkg = l >> 4;

  int nwg = gridDim.x;
  int bid = blockIdx.x;
  int sb = (bid & 7) * (nwg >> 3) + (bid >> 3);
  const int by = sb & 31, bx = sb >> 5;   // M/256 == 32 always
  const int m0 = by * G8M, n0 = bx * G8N;

  const char* Abase = (const char*)(A + (size_t)m0 * K);
  const char* Bbase = (const char*)(BT + (size_t)n0 * K);
  const int NT = K >> 6;

  f32x4 acc[8][4];
#pragma unroll
  for (int i = 0; i < 8; i++)
#pragma unroll
    for (int j = 0; j < 4; j++) acc[i][j] = (f32x4){0.f, 0.f, 0.f, 0.f};

  // byte offsets within one [256][32] kh-plane: row*64 + (lkg^(row&3))*16
  int aoff[2][4], boff[4];
#pragma unroll
  for (int mih = 0; mih < 2; mih++)
#pragma unroll
    for (int mi = 0; mi < 4; mi++) {
      int row = wr * 128 + (mih * 4 + mi) * 16 + lr;
      aoff[mih][mi] = row * 64 + ((lkg ^ (row & 3)) * 16);
    }
#pragma unroll
  for (int ni = 0; ni < 4; ni++) {
    int row = wc * 64 + ni * 16 + lr;
    boff[ni] = row * 64 + ((lkg ^ (row & 3)) * 16);
  }

  // stage one K-half (16KB): 2 loads/thread; linear LDS dest, inverse-swizzled src
#define STG8(arr, gbase, buf, kh, k0)                                          \
  do {                                                                         \
    _Pragma("unroll")                                                          \
    for (int ld = 0; ld < 2; ld++) {                                           \
      int off = (ld * 512 + t) * 16;                                           \
      int r = off >> 6;                                                        \
      int sg = ((off >> 4) & 3) ^ (r & 3);                                     \
      async16((char*)arr[buf][kh] + off,                                       \
              gbase + ((size_t)r * K + (k0) + (kh) * 32) * 2 + sg * 16);       \
    }                                                                          \
  } while (0)

  // prologue: tile 0 fully staged + drained
  STG8(As, Abase, 0, 0, 0);
  STG8(Bs, Bbase, 0, 0, 0);
  STG8(As, Abase, 0, 1, 0);
  STG8(Bs, Bbase, 0, 1, 0);
  asm volatile("s_waitcnt vmcnt(0)" ::: "memory");
  __syncthreads();

  for (int kt = 0; kt < NT; kt++) {
    const int cb = kt & 1;
    const int kn = (kt + 1 < NT) ? (kt + 1) * G8K : 0;  // dead-clamped stages
#pragma unroll
    for (int ph = 0; ph < 4; ph++) {
      const int kh = ph >> 1, mih = ph & 1;
      const char* Ap = (const char*)As[cb][kh];
      const char* Bp = (const char*)Bs[cb][kh];
      short8 a[4], b[4];
#pragma unroll
      for (int mi = 0; mi < 4; mi++) a[mi] = *(const short8*)(Ap + aoff[mih][mi]);
#pragma unroll
      for (int ni = 0; ni < 4; ni++) b[ni] = *(const short8*)(Bp + boff[ni]);
      // stage schedule (tile kt+1, dead buffer cb^1): ph0 Ak0, ph1 Bk0, ph2 Ak1, ph3 Bk1
      if (ph == 0) {
        STG8(As, Abase, cb ^ 1, 0, kn);
      } else if (ph == 1) {
        STG8(Bs, Bbase, cb ^ 1, 0, kn);
      } else if (ph == 2) {
        STG8(As, Abase, cb ^ 1, 1, kn);
      } else {
        STG8(Bs, Bbase, cb ^ 1, 1, kn);
      }
      if (ph & 1) asm volatile("s_waitcnt vmcnt(4)" ::: "memory");
      __builtin_amdgcn_s_barrier();
      asm volatile("s_waitcnt lgkmcnt(0)" ::: "memory");
      __builtin_amdgcn_sched_barrier(0);
      __builtin_amdgcn_s_setprio(1);
#pragma unroll
      for (int mi = 0; mi < 4; mi++)
#pragma unroll
        for (int ni = 0; ni < 4; ni++)
          acc[mih * 4 + mi][ni] = __builtin_amdgcn_mfma_f32_16x16x32_bf16(
              a[mi], b[ni], acc[mih * 4 + mi][ni], 0, 0, 0);
      __builtin_amdgcn_s_setprio(0);
      __builtin_amdgcn_s_barrier();
    }
  }
#undef STG8

#pragma unroll
  for (int I = 0; I < 8; I++) {
    int rowoff = (I >> 2) * 64 + (I & 3) * 16;
#pragma unroll
    for (int ni = 0; ni < 4; ni++)
#pragma unroll
      for (int j = 0; j < 4; j++) {
        int gm = m0 + wr * 128 + rowoff + lkg * 4 + j;
        int gn = n0 + wc * 64 + ni * 16 + lr;
        epi_write<EPI>(gm, gn, acc[I][ni][j], N, bias, resid, outF, outB);
      }
  }
}

// ---------------- causal flash attention (no-max softmax, seq-mi small-LDS) ----------------
#define KVB 64
#define QB2 128
#define PSTR 76

__global__ __launch_bounds__(256) void attn_k(
    const bf16* __restrict__ qg, const bf16* __restrict__ kg,
    const bf16* __restrict__ vtg, bf16* __restrict__ ctx) {
  const int bid = blockIdx.x;
  const int qt = (SEQLEN / QB2 - 1) - (bid >> 6);  // 15..0, long blocks first
  const int bh = bid & 63;
  const int q0 = qt * QB2;
  const int t = threadIdx.x, w = t >> 6, l = t & 63;
  const int lr = l & 15, lkg = l >> 4, lk = lkg * 8;

  const bf16* Q  = qg  + (size_t)bh * SEQLEN * HDIM;
  const bf16* Kg = kg  + (size_t)bh * SEQLEN * HDIM;
  const bf16* Vt = vtg + (size_t)bh * HDIM * SEQLEN;

  __shared__ bf16 Ks[KVB * PSTR];
  __shared__ bf16 Vs[HDIM * PSTR];
  __shared__ bf16 Ps[4][16 * PSTR];   // 16 rows per wave, shared by mi passes

  short8 qf[2][2];
#pragma unroll
  for (int mi = 0; mi < 2; mi++)
#pragma unroll
    for (int kk = 0; kk < 2; kk++)
      qf[mi][kk] = *(const short8*)&Q[(size_t)(q0 + w * 32 + mi * 16 + lr) * HDIM + kk * 32 + lk];

  const short8 bones = {0x3F80, 0x3F80, 0x3F80, 0x3F80, 0x3F80, 0x3F80, 0x3F80, 0x3F80};

  f32x4 o[2][4];
  f32x4 ol[2];
#pragma unroll
  for (int mi = 0; mi < 2; mi++) {
    ol[mi] = (f32x4){0.f, 0.f, 0.f, 0.f};
#pragma unroll
    for (int nh = 0; nh < 4; nh++) o[mi][nh] = (f32x4){0.f, 0.f, 0.f, 0.f};
  }

  const int srow = t >> 3;        // 0..31
  const int scc  = (t & 7) * 8;   // elem offset within 64-elem row

  const int ntiles = 2 * qt + 2;
  for (int tkv = 0; tkv < ntiles; tkv++) {
    const int kv0 = tkv * KVB;
#pragma unroll
    for (int r = 0; r < 2; r++) {
      int row = srow + r * 32;
      short8 kv = *(const short8*)&Kg[(size_t)(kv0 + row) * HDIM + scc];
      *(short8*)&Ks[row * PSTR + scc] = kv;
      short8 vv = *(const short8*)&Vt[(size_t)row * SEQLEN + kv0 + scc];
      *(short8*)&Vs[row * PSTR + scc] = vv;
    }
    __syncthreads();

    const bool active = (kv0 <= q0 + w * 32 + 31);
    if (active) {
      short8 kf[4][2];
#pragma unroll
      for (int ni = 0; ni < 4; ni++)
#pragma unroll
        for (int kk = 0; kk < 2; kk++)
          kf[ni][kk] = *(const short8*)&Ks[(ni * 16 + lr) * PSTR + kk * 32 + lk];
      f32x4 s[2][4];
#pragma unroll
      for (int mi = 0; mi < 2; mi++)
#pragma unroll
        for (int ni = 0; ni < 4; ni++) {
          f32x4 a = (f32x4){0.f, 0.f, 0.f, 0.f};
#pragma unroll
          for (int kk = 0; kk < 2; kk++)
            a = __builtin_amdgcn_mfma_f32_16x16x32_bf16(qf[mi][kk], kf[ni][kk], a, 0, 0, 0);
          s[mi][ni] = a;
        }
      if (tkv >= ntiles - 2) {  // diagonal region: causal mask
#pragma unroll
        for (int mi = 0; mi < 2; mi++)
#pragma unroll
          for (int ni = 0; ni < 4; ni++)
#pragma unroll
            for (int j = 0; j < 4; j++) {
              int qq = q0 + w * 32 + mi * 16 + lkg * 4 + j;
              int kv = kv0 + ni * 16 + lr;
              if (kv > qq) s[mi][ni][j] = -1e30f;
            }
      }
      // sequential mi passes through the shared 16-row P buffer
#pragma unroll
      for (int mi = 0; mi < 2; mi++) {
#pragma unroll
        for (int ni = 0; ni < 4; ni++)
#pragma unroll
          for (int j = 0; j < 4; j++)
            ((short*)Ps[w])[(lkg * 4 + j) * PSTR + ni * 16 + lr] =
                (short)__bfloat16_as_ushort(__float2bfloat16(exp2f(s[mi][ni][j])));
#pragma unroll
        for (int kk = 0; kk < 2; kk++) {
          short8 pa = *(const short8*)&Ps[w][lr * PSTR + kk * 32 + lk];
          ol[mi] = __builtin_amdgcn_mfma_f32_16x16x32_bf16(pa, bones, ol[mi], 0, 0, 0);
#pragma unroll
          for (int nh = 0; nh < 4; nh++) {
            short8 vb = *(const short8*)&Vs[(nh * 16 + lr) * PSTR + kk * 32 + lk];
            o[mi][nh] = __builtin_amdgcn_mfma_f32_16x16x32_bf16(pa, vb, o[mi][nh], 0, 0, 0);
          }
        }
      }
    }
    __syncthreads();
  }

  const int b_ = bh >> 4, h_ = bh & 15;
#pragma unroll
  for (int mi = 0; mi < 2; mi++)
#pragma unroll
    for (int j = 0; j < 4; j++) {
      float inv = 1.0f / ol[mi][j];
      int qq = q0 + w * 32 + mi * 16 + lkg * 4 + j;
      size_t base = (((size_t)b_ * SEQLEN + qq) * NHEADS + h_) * HDIM;
#pragma unroll
      for (int nh = 0; nh < 4; nh++)
        ctx[base + nh * 16 + lr] = __float2bfloat16(o[mi][nh][j] * inv);
    }
}

// ---------------- confidence gate ----------------
__global__ __launch_bounds__(256) void pool_partial_k(
    const float* __restrict__ xo, float* __restrict__ part) {
  int blk = blockIdx.x;
  int b_ = blk >> 4, ch = blk & 15;
  int t = threadIdx.x;
  f32x4 acc = (f32x4){0.f, 0.f, 0.f, 0.f};
  const float* base = xo + ((size_t)b_ * SEQLEN + (size_t)ch * 128) * D_MODELC;
  for (int r = 0; r < 128; r++)
    acc += ((const f32x4*)(base + (size_t)r * D_MODELC))[t];
  ((f32x4*)(part + (size_t)blk * D_MODELC))[t] = acc;
}

__global__ __launch_bounds__(256) void conf_k(
    const float* __restrict__ part, const float* __restrict__ Wc,
    const float* __restrict__ bc, float* __restrict__ outc) {
  int t = threadIdx.x;
  __shared__ float red[4];
  float total = 0.f;
  for (int b_ = 0; b_ < BATCHN; b_++) {
    f32x4 sum = (f32x4){0.f, 0.f, 0.f, 0.f};
    for (int ch = 0; ch < 16; ch++)
      sum += ((const f32x4*)(part + (size_t)(b_ * 16 + ch) * D_MODELC))[t];
    f32x4 wv = ((const f32x4*)Wc)[t];
    float d = (sum[0] * wv[0] + sum[1] * wv[1] + sum[2] * wv[2] + sum[3] * wv[3]) * (1.0f / SEQLEN);
#pragma unroll
    for (int m = 1; m < 64; m <<= 1) d += __shfl_xor(d, m);
    int wq = t >> 6, l = t & 63;
    if (l == 0) red[wq] = d;
    __syncthreads();
    float z = red[0] + red[1] + red[2] + red[3] + bc[0];
    total += 1.0f / (1.0f + __expf(-z));
    __syncthreads();
  }
  if (t == 0) outc[0] = total * (1.0f / BATCHN);
}

// ---------------- launch ----------------
extern "C" void kernel_launch(void* const* d_in, const int* in_sizes, int n_in,
                              void* d_out, int out_size, void* d_ws, size_t ws_size,
                              hipStream_t stream) {
  const float* x    = (const float*)d_in[0];
  const float* Wq   = (const float*)d_in[1];
  const float* Wk   = (const float*)d_in[2];
  const float* Wv   = (const float*)d_in[3];
  const float* Wo   = (const float*)d_in[4];
  const float* ln1g = (const float*)d_in[5];
  const float* ln1b = (const float*)d_in[6];
  const float* ln2g = (const float*)d_in[7];
  const float* ln2b = (const float*)d_in[8];
  const float* W1   = (const float*)d_in[9];
  const float* b1   = (const float*)d_in[10];
  const float* W2   = (const float*)d_in[11];
  const float* b2   = (const float*)d_in[12];
  const float* Wc   = (const float*)d_in[13];
  const float* bc   = (const float*)d_in[14];

  char* ws = (char*)d_ws;
  const size_t MB = 1024 * 1024;
  bf16* qkv   = (bf16*)(ws);                    // q,k [bh][S][64]; vT [bh][64][S]
  bf16* ctx   = (bf16*)(ws + 48 * MB);
  bf16* ff1   = (bf16*)(ws);                    // reuse qkv region (64MB)
  bf16* h     = (bf16*)(ws + 64 * MB);          // 16MB (h, then h2)
  bf16* WqkvT = (bf16*)(ws + 80 * MB);          // 6MB: [3072][1024]
  bf16* WoT   = (bf16*)(ws + 86 * MB);          // 2MB
  bf16* W1T   = (bf16*)(ws + 88 * MB);          // 8MB: [4096][1024]
  bf16* W2T   = (bf16*)(ws + 96 * MB);          // 8MB: [1024][4096]
  float* part = (float*)(ws + 104 * MB);        // 256KB

  float* xout = (float*)d_out;
  dim3 blk(256);
  dim3 blk512(512);

  const float SCL2 = 0.125f * 1.44269504f;  // fold score-scale * log2(e) into Wq

  // weights -> bf16, transposed to [N][K]
  transpose_bf16_k<<<dim3(32, 32), blk, 0, stream>>>(Wq, WqkvT, 1024, 1024, SCL2);
  transpose_bf16_k<<<dim3(32, 32), blk, 0, stream>>>(Wk, WqkvT + 1024 * 1024, 1024, 1024, 1.0f);
  transpose_bf16_k<<<dim3(32, 32), blk, 0, stream>>>(Wv, WqkvT + 2 * 1024 * 1024, 1024, 1024, 1.0f);
  transpose_bf16_k<<<dim3(32, 32), blk, 0, stream>>>(Wo, WoT, 1024, 1024, 1.0f);
  transpose_bf16_k<<<dim3(128, 32), blk, 0, stream>>>(W1, W1T, 1024, 4096, 1.0f);
  transpose_bf16_k<<<dim3(32, 128), blk, 0, stream>>>(W2, W2T, 4096, 1024, 1.0f);

  // LN1 -> h (bf16)
  ln_bf16_k<<<MTOT, blk, 0, stream>>>(x, ln1g, ln1b, h);
  // QKV (8-phase 256^2): -> q,k [B,H,S,64]; v transposed [B,H,64,S]
  gemm8p<EPI_QKV><<<dim3((3072 / G8N) * 32), blk512, 0, stream>>>(
      h, WqkvT, 3072, 1024, nullptr, nullptr, nullptr, qkv);
  // attention -> ctx [M][1024]
  attn_k<<<dim3((SEQLEN / QB2) * 64), blk, 0, stream>>>(
      qkv, qkv + (size_t)MTOT * D_MODELC, qkv + 2 * (size_t)MTOT * D_MODELC, ctx);
  // x1 = x + ctx @ Wo  (fp32, into d_out) -- skinny N: keep 128^2
  gemm_nt<EPI_RESID><<<dim3(1024 / BN, MTOT / BM), blk, 0, stream>>>(
      ctx, WoT, MTOT, 1024, 1024, nullptr, x, xout, nullptr);
  // LN2 -> h2 (bf16)
  ln_bf16_k<<<MTOT, blk, 0, stream>>>(xout, ln2g, ln2b, h);
  // ff1 = relu(h2 @ W1 + b1) (bf16) (8-phase 256^2)
  gemm8p<EPI_BIAS_RELU><<<dim3((4096 / G8N) * 32), blk512, 0, stream>>>(
      h, W1T, 4096, 1024, b1, nullptr, nullptr, ff1);
  // x_out = x1 + ff1 @ W2 + b2 (fp32, in-place in d_out) -- skinny N: 128^2
  gemm_nt<EPI_BIAS_RESID><<<dim3(1024 / BN, MTOT / BM), blk, 0, stream>>>(
      ff1, W2T, MTOT, 1024, 4096, b2, xout, xout, nullptr);
  // confidence gate
  pool_partial_k<<<64, blk, 0, stream>>>(xout, part);
  conf_k<<<1, blk, 0, stream>>>(part, Wc, bc, xout + (size_t)MTOT * D_MODELC);
}

// Round 16
// 412.373 us; speedup vs baseline: 1.1789x; 1.1789x over previous
//
#include <hip/hip_runtime.h>
#include <hip/hip_bf16.h>

typedef __hip_bfloat16 bf16;
typedef __attribute__((ext_vector_type(8))) short short8;
typedef __attribute__((ext_vector_type(4))) float f32x4;

#define D_MODELC 1024
#define D_FFC    4096
#define NHEADS   16
#define HDIM     64
#define SEQLEN   2048
#define BATCHN   4
#define MTOT     (BATCHN * SEQLEN)   // 8192

// ---------------- async global->LDS (16B per lane) ----------------
__device__ __forceinline__ void async16(void* lds, const void* g) {
  __builtin_amdgcn_global_load_lds(
      (const __attribute__((address_space(1))) unsigned int*)g,
      (__attribute__((address_space(3))) unsigned int*)lds, 16, 0, 0);
}

// ---------------- weight transpose-convert: src[R][C] f32 -> dst[C][R] bf16 * scale ----------------
__global__ __launch_bounds__(256) void transpose_bf16_k(
    const float* __restrict__ src, bf16* __restrict__ dst, int R, int C, float scale) {
  __shared__ float tile[32][33];
  int tx = threadIdx.x & 31, ty = threadIdx.x >> 5;  // ty: 0..7
  int r0 = blockIdx.y * 32, c0 = blockIdx.x * 32;
#pragma unroll
  for (int i = 0; i < 4; i++) {
    int r = ty + i * 8;
    tile[r][tx] = src[(size_t)(r0 + r) * C + c0 + tx];
  }
  __syncthreads();
#pragma unroll
  for (int i = 0; i < 4; i++) {
    int c = ty + i * 8;
    dst[(size_t)(c0 + c) * R + r0 + tx] = __float2bfloat16(tile[tx][c] * scale);
  }
}

// ---------------- LayerNorm f32 row (1024) -> bf16 ----------------
__global__ __launch_bounds__(256) void ln_bf16_k(
    const float* __restrict__ x, const float* __restrict__ g,
    const float* __restrict__ b, bf16* __restrict__ out) {
  int row = blockIdx.x;
  int t = threadIdx.x;
  f32x4 v = ((const f32x4*)(x + (size_t)row * D_MODELC))[t];
  float s = v[0] + v[1] + v[2] + v[3];
  float ss = v[0] * v[0] + v[1] * v[1] + v[2] * v[2] + v[3] * v[3];
#pragma unroll
  for (int m = 1; m < 64; m <<= 1) {
    s += __shfl_xor(s, m);
    ss += __shfl_xor(ss, m);
  }
  __shared__ float red[8];
  int w = t >> 6, l = t & 63;
  if (l == 0) { red[w] = s; red[4 + w] = ss; }
  __syncthreads();
  s = red[0] + red[1] + red[2] + red[3];
  ss = red[4] + red[5] + red[6] + red[7];
  float mean = s * (1.0f / D_MODELC);
  float var = ss * (1.0f / D_MODELC) - mean * mean;
  float rs = rsqrtf(var + 1e-5f);
  f32x4 gv = ((const f32x4*)g)[t];
  f32x4 bv = ((const f32x4*)b)[t];
  unsigned short u[4];
#pragma unroll
  for (int j = 0; j < 4; j++) {
    float o = (v[j] - mean) * rs * gv[j] + bv[j];
    u[j] = __bfloat16_as_ushort(__float2bfloat16(o));
  }
  unsigned int lo = (unsigned int)u[0] | ((unsigned int)u[1] << 16);
  unsigned int hi = (unsigned int)u[2] | ((unsigned int)u[3] << 16);
  ((uint2*)(out + (size_t)row * D_MODELC))[t] = make_uint2(lo, hi);
}

enum { EPI_QKV = 0, EPI_RESID = 1, EPI_BIAS_RELU = 2, EPI_BIAS_RESID = 3 };

// ---------------- epilogue element write ----------------
template <int EPI>
__device__ __forceinline__ void epi_write(
    int gm, int gn, float v, int N,
    const float* __restrict__ bias, const float* __restrict__ resid,
    float* __restrict__ outF, bf16* __restrict__ outB) {
  if constexpr (EPI == EPI_QKV) {
    int sel = gn >> 10, d = gn & 1023;
    int b_ = gm >> 11, s_ = gm & 2047;
    int h2 = d >> 6, dd = d & 63;
    size_t bh = (size_t)b_ * NHEADS + h2;
    size_t dst;
    if (sel < 2) {
      dst = (size_t)sel * ((size_t)MTOT * D_MODELC) + (bh * SEQLEN + s_) * HDIM + dd;
    } else {
      // V stored TRANSPOSED: [bh][d][S]
      dst = 2 * ((size_t)MTOT * D_MODELC) + (bh * HDIM + dd) * SEQLEN + s_;
    }
    outB[dst] = __float2bfloat16(v);
  } else if constexpr (EPI == EPI_RESID) {
    size_t idx = (size_t)gm * N + gn;
    outF[idx] = resid[idx] + v;
  } else if constexpr (EPI == EPI_BIAS_RELU) {
    float z = v + bias[gn];
    outB[(size_t)gm * N + gn] = __float2bfloat16(z > 0.f ? z : 0.f);
  } else {
    size_t idx = (size_t)gm * N + gn;
    outF[idx] = resid[idx] + v + bias[gn];
  }
}

// ---------------- 128x128 bf16 NT GEMM (proven m97-structure) ----------------
#define BM 128
#define BN 128
#define BKK 64

template <int EPI>
__global__ __launch_bounds__(256) void gemm_nt(
    const bf16* __restrict__ A, const bf16* __restrict__ BT, int M, int N, int K,
    const float* __restrict__ bias, const float* __restrict__ resid,
    float* __restrict__ outF, bf16* __restrict__ outB) {
  __shared__ bf16 As[BM * BKK];
  __shared__ bf16 Bs[BN * BKK];
  const int t = threadIdx.x;
  const int l = t & 63;
  const int w = t >> 6;
  const int wm = w >> 1, wn = w & 1;

  int nwg = gridDim.x * gridDim.y;
  int bid = blockIdx.y * gridDim.x + blockIdx.x;
  if ((nwg & 7) == 0) {
    int q8 = nwg >> 3;
    bid = (bid & 7) * q8 + (bid >> 3);
  }
  const int bx = bid % gridDim.x, by = bid / gridDim.x;
  const int m0 = by * BM, n0 = bx * BN;
  const int lr = l & 15, lkg = l >> 4;

  f32x4 acc[4][4];
#pragma unroll
  for (int i = 0; i < 4; i++)
#pragma unroll
    for (int j = 0; j < 4; j++) acc[i][j] = (f32x4){0.f, 0.f, 0.f, 0.f};

  const char* Abase = (const char*)(A + (size_t)m0 * K);
  const char* Bbase = (const char*)(BT + (size_t)n0 * K);

  for (int k0 = 0; k0 < K; k0 += BKK) {
#pragma unroll
    for (int c = 0; c < 4; c++) {
      int off = (c * 256 + t) * 16;
      int r = off >> 7;
      int sg = ((off >> 4) & 7) ^ (r & 7);
      async16((char*)As + off, Abase + ((size_t)r * K + k0) * 2 + sg * 16);
      async16((char*)Bs + off, Bbase + ((size_t)r * K + k0) * 2 + sg * 16);
    }
    __syncthreads();
    short8 a[2][4], b[2][4];
#pragma unroll
    for (int kk = 0; kk < 2; kk++) {
#pragma unroll
      for (int mi = 0; mi < 4; mi++) {
        int row = wm * 64 + mi * 16 + lr;
        int sl = (kk * 4 + lkg) ^ (row & 7);
        a[kk][mi] = *(const short8*)((const char*)As + row * 128 + sl * 16);
      }
#pragma unroll
      for (int ni = 0; ni < 4; ni++) {
        int row = wn * 64 + ni * 16 + lr;
        int sl = (kk * 4 + lkg) ^ (row & 7);
        b[kk][ni] = *(const short8*)((const char*)Bs + row * 128 + sl * 16);
      }
    }
#pragma unroll
    for (int kk = 0; kk < 2; kk++)
#pragma unroll
      for (int mi = 0; mi < 4; mi++)
#pragma unroll
        for (int ni = 0; ni < 4; ni++)
          acc[mi][ni] = __builtin_amdgcn_mfma_f32_16x16x32_bf16(a[kk][mi], b[kk][ni], acc[mi][ni], 0, 0, 0);
    __syncthreads();
  }

#pragma unroll
  for (int mi = 0; mi < 4; mi++)
#pragma unroll
    for (int ni = 0; ni < 4; ni++)
#pragma unroll
      for (int j = 0; j < 4; j++) {
        int gm = m0 + wm * 64 + mi * 16 + lkg * 4 + j;
        int gn = n0 + wn * 64 + ni * 16 + lr;
        epi_write<EPI>(gm, gn, acc[mi][ni][j], N, bias, resid, outF, outB);
      }
}

// ---------------- causal flash attention (no-max softmax, seq-mi small-LDS) ----------------
// QB=128 (4 waves x 32 q-rows). Ps 16 rows/wave, two mi fragments pass through it
// SEQUENTIALLY (same-wave write->read, no barrier). No-max exp2 softmax (Wq
// pre-scaled by 0.125*log2e), row-sum via ones-MFMA, conflict-free PSTR=76.
#define KVB 64
#define QB2 128
#define PSTR 76

__global__ __launch_bounds__(256) void attn_k(
    const bf16* __restrict__ qg, const bf16* __restrict__ kg,
    const bf16* __restrict__ vtg, bf16* __restrict__ ctx) {
  const int bid = blockIdx.x;
  const int qt = (SEQLEN / QB2 - 1) - (bid >> 6);  // 15..0, long blocks first
  const int bh = bid & 63;
  const int q0 = qt * QB2;
  const int t = threadIdx.x, w = t >> 6, l = t & 63;
  const int lr = l & 15, lkg = l >> 4, lk = lkg * 8;

  const bf16* Q  = qg  + (size_t)bh * SEQLEN * HDIM;
  const bf16* Kg = kg  + (size_t)bh * SEQLEN * HDIM;
  const bf16* Vt = vtg + (size_t)bh * HDIM * SEQLEN;

  __shared__ bf16 Ks[KVB * PSTR];
  __shared__ bf16 Vs[HDIM * PSTR];
  __shared__ bf16 Ps[4][16 * PSTR];   // 16 rows per wave, shared by mi passes

  short8 qf[2][2];
#pragma unroll
  for (int mi = 0; mi < 2; mi++)
#pragma unroll
    for (int kk = 0; kk < 2; kk++)
      qf[mi][kk] = *(const short8*)&Q[(size_t)(q0 + w * 32 + mi * 16 + lr) * HDIM + kk * 32 + lk];

  const short8 bones = {0x3F80, 0x3F80, 0x3F80, 0x3F80, 0x3F80, 0x3F80, 0x3F80, 0x3F80};

  f32x4 o[2][4];
  f32x4 ol[2];
#pragma unroll
  for (int mi = 0; mi < 2; mi++) {
    ol[mi] = (f32x4){0.f, 0.f, 0.f, 0.f};
#pragma unroll
    for (int nh = 0; nh < 4; nh++) o[mi][nh] = (f32x4){0.f, 0.f, 0.f, 0.f};
  }

  const int srow = t >> 3;        // 0..31
  const int scc  = (t & 7) * 8;   // elem offset within 64-elem row

  const int ntiles = 2 * qt + 2;
  for (int tkv = 0; tkv < ntiles; tkv++) {
    const int kv0 = tkv * KVB;
#pragma unroll
    for (int r = 0; r < 2; r++) {
      int row = srow + r * 32;
      short8 kv = *(const short8*)&Kg[(size_t)(kv0 + row) * HDIM + scc];
      *(short8*)&Ks[row * PSTR + scc] = kv;
      short8 vv = *(const short8*)&Vt[(size_t)row * SEQLEN + kv0 + scc];
      *(short8*)&Vs[row * PSTR + scc] = vv;
    }
    __syncthreads();

    const bool active = (kv0 <= q0 + w * 32 + 31);
    if (active) {
      short8 kf[4][2];
#pragma unroll
      for (int ni = 0; ni < 4; ni++)
#pragma unroll
        for (int kk = 0; kk < 2; kk++)
          kf[ni][kk] = *(const short8*)&Ks[(ni * 16 + lr) * PSTR + kk * 32 + lk];
      f32x4 s[2][4];
#pragma unroll
      for (int mi = 0; mi < 2; mi++)
#pragma unroll
        for (int ni = 0; ni < 4; ni++) {
          f32x4 a = (f32x4){0.f, 0.f, 0.f, 0.f};
#pragma unroll
          for (int kk = 0; kk < 2; kk++)
            a = __builtin_amdgcn_mfma_f32_16x16x32_bf16(qf[mi][kk], kf[ni][kk], a, 0, 0, 0);
          s[mi][ni] = a;
        }
      if (tkv >= ntiles - 2) {  // diagonal region: causal mask
#pragma unroll
        for (int mi = 0; mi < 2; mi++)
#pragma unroll
          for (int ni = 0; ni < 4; ni++)
#pragma unroll
            for (int j = 0; j < 4; j++) {
              int qq = q0 + w * 32 + mi * 16 + lkg * 4 + j;
              int kv = kv0 + ni * 16 + lr;
              if (kv > qq) s[mi][ni][j] = -1e30f;
            }
      }
      // sequential mi passes through the shared 16-row P buffer
#pragma unroll
      for (int mi = 0; mi < 2; mi++) {
#pragma unroll
        for (int ni = 0; ni < 4; ni++)
#pragma unroll
          for (int j = 0; j < 4; j++)
            ((short*)Ps[w])[(lkg * 4 + j) * PSTR + ni * 16 + lr] =
                (short)__bfloat16_as_ushort(__float2bfloat16(exp2f(s[mi][ni][j])));
#pragma unroll
        for (int kk = 0; kk < 2; kk++) {
          short8 pa = *(const short8*)&Ps[w][lr * PSTR + kk * 32 + lk];
          ol[mi] = __builtin_amdgcn_mfma_f32_16x16x32_bf16(pa, bones, ol[mi], 0, 0, 0);
#pragma unroll
          for (int nh = 0; nh < 4; nh++) {
            short8 vb = *(const short8*)&Vs[(nh * 16 + lr) * PSTR + kk * 32 + lk];
            o[mi][nh] = __builtin_amdgcn_mfma_f32_16x16x32_bf16(pa, vb, o[mi][nh], 0, 0, 0);
          }
        }
      }
    }
    __syncthreads();
  }

  const int b_ = bh >> 4, h_ = bh & 15;
#pragma unroll
  for (int mi = 0; mi < 2; mi++)
#pragma unroll
    for (int j = 0; j < 4; j++) {
      float inv = 1.0f / ol[mi][j];
      int qq = q0 + w * 32 + mi * 16 + lkg * 4 + j;
      size_t base = (((size_t)b_ * SEQLEN + qq) * NHEADS + h_) * HDIM;
#pragma unroll
      for (int nh = 0; nh < 4; nh++)
        ctx[base + nh * 16 + lr] = __float2bfloat16(o[mi][nh][j] * inv);
    }
}

// ---------------- confidence gate ----------------
__global__ __launch_bounds__(256) void pool_partial_k(
    const float* __restrict__ xo, float* __restrict__ part) {
  int blk = blockIdx.x;
  int b_ = blk >> 4, ch = blk & 15;
  int t = threadIdx.x;
  f32x4 acc = (f32x4){0.f, 0.f, 0.f, 0.f};
  const float* base = xo + ((size_t)b_ * SEQLEN + (size_t)ch * 128) * D_MODELC;
  for (int r = 0; r < 128; r++)
    acc += ((const f32x4*)(base + (size_t)r * D_MODELC))[t];
  ((f32x4*)(part + (size_t)blk * D_MODELC))[t] = acc;
}

__global__ __launch_bounds__(256) void conf_k(
    const float* __restrict__ part, const float* __restrict__ Wc,
    const float* __restrict__ bc, float* __restrict__ outc) {
  int t = threadIdx.x;
  __shared__ float red[4];
  float total = 0.f;
  for (int b_ = 0; b_ < BATCHN; b_++) {
    f32x4 sum = (f32x4){0.f, 0.f, 0.f, 0.f};
    for (int ch = 0; ch < 16; ch++)
      sum += ((const f32x4*)(part + (size_t)(b_ * 16 + ch) * D_MODELC))[t];
    f32x4 wv = ((const f32x4*)Wc)[t];
    float d = (sum[0] * wv[0] + sum[1] * wv[1] + sum[2] * wv[2] + sum[3] * wv[3]) * (1.0f / SEQLEN);
#pragma unroll
    for (int m = 1; m < 64; m <<= 1) d += __shfl_xor(d, m);
    int wq = t >> 6, l = t & 63;
    if (l == 0) red[wq] = d;
    __syncthreads();
    float z = red[0] + red[1] + red[2] + red[3] + bc[0];
    total += 1.0f / (1.0f + __expf(-z));
    __syncthreads();
  }
  if (t == 0) outc[0] = total * (1.0f / BATCHN);
}

// ---------------- launch ----------------
extern "C" void kernel_launch(void* const* d_in, const int* in_sizes, int n_in,
                              void* d_out, int out_size, void* d_ws, size_t ws_size,
                              hipStream_t stream) {
  const float* x    = (const float*)d_in[0];
  const float* Wq   = (const float*)d_in[1];
  const float* Wk   = (const float*)d_in[2];
  const float* Wv   = (const float*)d_in[3];
  const float* Wo   = (const float*)d_in[4];
  const float* ln1g = (const float*)d_in[5];
  const float* ln1b = (const float*)d_in[6];
  const float* ln2g = (const float*)d_in[7];
  const float* ln2b = (const float*)d_in[8];
  const float* W1   = (const float*)d_in[9];
  const float* b1   = (const float*)d_in[10];
  const float* W2   = (const float*)d_in[11];
  const float* b2   = (const float*)d_in[12];
  const float* Wc   = (const float*)d_in[13];
  const float* bc   = (const float*)d_in[14];

  char* ws = (char*)d_ws;
  const size_t MB = 1024 * 1024;
  bf16* qkv   = (bf16*)(ws);                    // q,k [bh][S][64]; vT [bh][64][S]
  bf16* ctx   = (bf16*)(ws + 48 * MB);
  bf16* ff1   = (bf16*)(ws);                    // reuse qkv region (64MB)
  bf16* h     = (bf16*)(ws + 64 * MB);          // 16MB (h, then h2)
  bf16* WqkvT = (bf16*)(ws + 80 * MB);          // 6MB: [3072][1024]
  bf16* WoT   = (bf16*)(ws + 86 * MB);          // 2MB
  bf16* W1T   = (bf16*)(ws + 88 * MB);          // 8MB: [4096][1024]
  bf16* W2T   = (bf16*)(ws + 96 * MB);          // 8MB: [1024][4096]
  float* part = (float*)(ws + 104 * MB);        // 256KB

  float* xout = (float*)d_out;
  dim3 blk(256);

  const float SCL2 = 0.125f * 1.44269504f;  // fold score-scale * log2(e) into Wq

  // weights -> bf16, transposed to [N][K]
  transpose_bf16_k<<<dim3(32, 32), blk, 0, stream>>>(Wq, WqkvT, 1024, 1024, SCL2);
  transpose_bf16_k<<<dim3(32, 32), blk, 0, stream>>>(Wk, WqkvT + 1024 * 1024, 1024, 1024, 1.0f);
  transpose_bf16_k<<<dim3(32, 32), blk, 0, stream>>>(Wv, WqkvT + 2 * 1024 * 1024, 1024, 1024, 1.0f);
  transpose_bf16_k<<<dim3(32, 32), blk, 0, stream>>>(Wo, WoT, 1024, 1024, 1.0f);
  transpose_bf16_k<<<dim3(128, 32), blk, 0, stream>>>(W1, W1T, 1024, 4096, 1.0f);
  transpose_bf16_k<<<dim3(32, 128), blk, 0, stream>>>(W2, W2T, 4096, 1024, 1.0f);

  // LN1 -> h (bf16)
  ln_bf16_k<<<MTOT, blk, 0, stream>>>(x, ln1g, ln1b, h);
  // QKV: -> q,k [B,H,S,64]; v transposed [B,H,64,S]
  gemm_nt<EPI_QKV><<<dim3(3072 / BN, MTOT / BM), blk, 0, stream>>>(
      h, WqkvT, MTOT, 3072, 1024, nullptr, nullptr, nullptr, qkv);
  // attention -> ctx [M][1024]
  attn_k<<<dim3((SEQLEN / QB2) * 64), blk, 0, stream>>>(
      qkv, qkv + (size_t)MTOT * D_MODELC, qkv + 2 * (size_t)MTOT * D_MODELC, ctx);
  // x1 = x + ctx @ Wo  (fp32, into d_out)
  gemm_nt<EPI_RESID><<<dim3(1024 / BN, MTOT / BM), blk, 0, stream>>>(
      ctx, WoT, MTOT, 1024, 1024, nullptr, x, xout, nullptr);
  // LN2 -> h2 (bf16)
  ln_bf16_k<<<MTOT, blk, 0, stream>>>(xout, ln2g, ln2b, h);
  // ff1 = relu(h2 @ W1 + b1) (bf16)
  gemm_nt<EPI_BIAS_RELU><<<dim3(4096 / BN, MTOT / BM), blk, 0, stream>>>(
      h, W1T, MTOT, 4096, 1024, b1, nullptr, nullptr, ff1);
  // x_out = x1 + ff1 @ W2 + b2 (fp32, in-place in d_out)
  gemm_nt<EPI_BIAS_RESID><<<dim3(1024 / BN, MTOT / BM), blk, 0, stream>>>(
      ff1, W2T, MTOT, 1024, 4096, b2, xout, xout, nullptr);
  // confidence gate
  pool_partial_k<<<64, blk, 0, stream>>>(xout, part);
  conf_k<<<1, blk, 0, stream>>>(part, Wc, bc, xout + (size_t)MTOT * D_MODELC);
}

// Round 17
// 401.396 us; speedup vs baseline: 1.2111x; 1.0273x over previous
//
#include <hip/hip_runtime.h>
#include <hip/hip_bf16.h>

typedef __hip_bfloat16 bf16;
typedef __attribute__((ext_vector_type(8))) short short8;
typedef __attribute__((ext_vector_type(4))) float f32x4;

#define D_MODELC 1024
#define D_FFC    4096
#define NHEADS   16
#define HDIM     64
#define SEQLEN   2048
#define BATCHN   4
#define MTOT     (BATCHN * SEQLEN)   // 8192

// ---------------- async global->LDS (16B per lane) ----------------
__device__ __forceinline__ void async16(void* lds, const void* g) {
  __builtin_amdgcn_global_load_lds(
      (const __attribute__((address_space(1))) unsigned int*)g,
      (__attribute__((address_space(3))) unsigned int*)lds, 16, 0, 0);
}

// ---------------- weight transpose-convert: src[R][C] f32 -> dst[C][R] bf16 * scale ----------------
__global__ __launch_bounds__(256) void transpose_bf16_k(
    const float* __restrict__ src, bf16* __restrict__ dst, int R, int C, float scale) {
  __shared__ float tile[32][33];
  int tx = threadIdx.x & 31, ty = threadIdx.x >> 5;  // ty: 0..7
  int r0 = blockIdx.y * 32, c0 = blockIdx.x * 32;
#pragma unroll
  for (int i = 0; i < 4; i++) {
    int r = ty + i * 8;
    tile[r][tx] = src[(size_t)(r0 + r) * C + c0 + tx];
  }
  __syncthreads();
#pragma unroll
  for (int i = 0; i < 4; i++) {
    int c = ty + i * 8;
    dst[(size_t)(c0 + c) * R + r0 + tx] = __float2bfloat16(tile[tx][c] * scale);
  }
}

// ---------------- LayerNorm f32 row (1024) -> bf16 ----------------
__global__ __launch_bounds__(256) void ln_bf16_k(
    const float* __restrict__ x, const float* __restrict__ g,
    const float* __restrict__ b, bf16* __restrict__ out) {
  int row = blockIdx.x;
  int t = threadIdx.x;
  f32x4 v = ((const f32x4*)(x + (size_t)row * D_MODELC))[t];
  float s = v[0] + v[1] + v[2] + v[3];
  float ss = v[0] * v[0] + v[1] * v[1] + v[2] * v[2] + v[3] * v[3];
#pragma unroll
  for (int m = 1; m < 64; m <<= 1) {
    s += __shfl_xor(s, m);
    ss += __shfl_xor(ss, m);
  }
  __shared__ float red[8];
  int w = t >> 6, l = t & 63;
  if (l == 0) { red[w] = s; red[4 + w] = ss; }
  __syncthreads();
  s = red[0] + red[1] + red[2] + red[3];
  ss = red[4] + red[5] + red[6] + red[7];
  float mean = s * (1.0f / D_MODELC);
  float var = ss * (1.0f / D_MODELC) - mean * mean;
  float rs = rsqrtf(var + 1e-5f);
  f32x4 gv = ((const f32x4*)g)[t];
  f32x4 bv = ((const f32x4*)b)[t];
  unsigned short u[4];
#pragma unroll
  for (int j = 0; j < 4; j++) {
    float o = (v[j] - mean) * rs * gv[j] + bv[j];
    u[j] = __bfloat16_as_ushort(__float2bfloat16(o));
  }
  unsigned int lo = (unsigned int)u[0] | ((unsigned int)u[1] << 16);
  unsigned int hi = (unsigned int)u[2] | ((unsigned int)u[3] << 16);
  ((uint2*)(out + (size_t)row * D_MODELC))[t] = make_uint2(lo, hi);
}

enum { EPI_QKV = 0, EPI_RESID = 1, EPI_BIAS_RELU = 2, EPI_BIAS_RESID = 3 };

// ---------------- epilogue element write ----------------
template <int EPI>
__device__ __forceinline__ void epi_write(
    int gm, int gn, float v, int N,
    const float* __restrict__ bias, const float* __restrict__ resid,
    float* __restrict__ outF, bf16* __restrict__ outB) {
  if constexpr (EPI == EPI_QKV) {
    int sel = gn >> 10, d = gn & 1023;
    int b_ = gm >> 11, s_ = gm & 2047;
    int h2 = d >> 6, dd = d & 63;
    size_t bh = (size_t)b_ * NHEADS + h2;
    size_t dst;
    if (sel < 2) {
      dst = (size_t)sel * ((size_t)MTOT * D_MODELC) + (bh * SEQLEN + s_) * HDIM + dd;
    } else {
      // V stored TRANSPOSED: [bh][d][S]
      dst = 2 * ((size_t)MTOT * D_MODELC) + (bh * HDIM + dd) * SEQLEN + s_;
    }
    outB[dst] = __float2bfloat16(v);
  } else if constexpr (EPI == EPI_RESID) {
    size_t idx = (size_t)gm * N + gn;
    outF[idx] = resid[idx] + v;
  } else if constexpr (EPI == EPI_BIAS_RELU) {
    float z = v + bias[gn];
    outB[(size_t)gm * N + gn] = __float2bfloat16(z > 0.f ? z : 0.f);
  } else {
    size_t idx = (size_t)gm * N + gn;
    outF[idx] = resid[idx] + v + bias[gn];
  }
}

// ---------------- 128x128 bf16 NT GEMM (proven m97-structure) ----------------
#define BM 128
#define BN 128
#define BKK 64

template <int EPI>
__global__ __launch_bounds__(256) void gemm_nt(
    const bf16* __restrict__ A, const bf16* __restrict__ BT, int M, int N, int K,
    const float* __restrict__ bias, const float* __restrict__ resid,
    float* __restrict__ outF, bf16* __restrict__ outB) {
  __shared__ bf16 As[BM * BKK];
  __shared__ bf16 Bs[BN * BKK];
  const int t = threadIdx.x;
  const int l = t & 63;
  const int w = t >> 6;
  const int wm = w >> 1, wn = w & 1;

  int nwg = gridDim.x * gridDim.y;
  int bid = blockIdx.y * gridDim.x + blockIdx.x;
  if ((nwg & 7) == 0) {
    int q8 = nwg >> 3;
    bid = (bid & 7) * q8 + (bid >> 3);
  }
  const int bx = bid % gridDim.x, by = bid / gridDim.x;
  const int m0 = by * BM, n0 = bx * BN;
  const int lr = l & 15, lkg = l >> 4;

  f32x4 acc[4][4];
#pragma unroll
  for (int i = 0; i < 4; i++)
#pragma unroll
    for (int j = 0; j < 4; j++) acc[i][j] = (f32x4){0.f, 0.f, 0.f, 0.f};

  const char* Abase = (const char*)(A + (size_t)m0 * K);
  const char* Bbase = (const char*)(BT + (size_t)n0 * K);

  for (int k0 = 0; k0 < K; k0 += BKK) {
#pragma unroll
    for (int c = 0; c < 4; c++) {
      int off = (c * 256 + t) * 16;
      int r = off >> 7;
      int sg = ((off >> 4) & 7) ^ (r & 7);
      async16((char*)As + off, Abase + ((size_t)r * K + k0) * 2 + sg * 16);
      async16((char*)Bs + off, Bbase + ((size_t)r * K + k0) * 2 + sg * 16);
    }
    __syncthreads();
    short8 a[2][4], b[2][4];
#pragma unroll
    for (int kk = 0; kk < 2; kk++) {
#pragma unroll
      for (int mi = 0; mi < 4; mi++) {
        int row = wm * 64 + mi * 16 + lr;
        int sl = (kk * 4 + lkg) ^ (row & 7);
        a[kk][mi] = *(const short8*)((const char*)As + row * 128 + sl * 16);
      }
#pragma unroll
      for (int ni = 0; ni < 4; ni++) {
        int row = wn * 64 + ni * 16 + lr;
        int sl = (kk * 4 + lkg) ^ (row & 7);
        b[kk][ni] = *(const short8*)((const char*)Bs + row * 128 + sl * 16);
      }
    }
#pragma unroll
    for (int kk = 0; kk < 2; kk++)
#pragma unroll
      for (int mi = 0; mi < 4; mi++)
#pragma unroll
        for (int ni = 0; ni < 4; ni++)
          acc[mi][ni] = __builtin_amdgcn_mfma_f32_16x16x32_bf16(a[kk][mi], b[kk][ni], acc[mi][ni], 0, 0, 0);
    __syncthreads();
  }

#pragma unroll
  for (int mi = 0; mi < 4; mi++)
#pragma unroll
    for (int ni = 0; ni < 4; ni++)
#pragma unroll
      for (int j = 0; j < 4; j++) {
        int gm = m0 + wm * 64 + mi * 16 + lkg * 4 + j;
        int gn = n0 + wn * 64 + ni * 16 + lr;
        epi_write<EPI>(gm, gn, acc[mi][ni][j], N, bias, resid, outF, outB);
      }
}

// ---------------- causal flash attention (no-max softmax, seq-mi, lean VALU) ----------------
// QB=128 (4 waves x 32 q-rows). Ps 16 rows/wave, mi fragments sequential.
// VALU diet: raw v_exp_f32 via __builtin_amdgcn_exp2f (no ocml wrapper) and
// TRUNCATION cast P->bf16 (1 op vs ~4 for RNE). Truncation biases P low <=0.4%
// avg, but appears in BOTH P.V and the row-sum l -> ratio cancels to 1st order.
#define KVB 64
#define QB2 128
#define PSTR 76

__device__ __forceinline__ short trunc_bf16(float x) {
  return (short)(__float_as_uint(x) >> 16);
}

__global__ __launch_bounds__(256) void attn_k(
    const bf16* __restrict__ qg, const bf16* __restrict__ kg,
    const bf16* __restrict__ vtg, bf16* __restrict__ ctx) {
  const int bid = blockIdx.x;
  const int qt = (SEQLEN / QB2 - 1) - (bid >> 6);  // 15..0, long blocks first
  const int bh = bid & 63;
  const int q0 = qt * QB2;
  const int t = threadIdx.x, w = t >> 6, l = t & 63;
  const int lr = l & 15, lkg = l >> 4, lk = lkg * 8;

  const bf16* Q  = qg  + (size_t)bh * SEQLEN * HDIM;
  const bf16* Kg = kg  + (size_t)bh * SEQLEN * HDIM;
  const bf16* Vt = vtg + (size_t)bh * HDIM * SEQLEN;

  __shared__ bf16 Ks[KVB * PSTR];
  __shared__ bf16 Vs[HDIM * PSTR];
  __shared__ bf16 Ps[4][16 * PSTR];   // 16 rows per wave, shared by mi passes

  short8 qf[2][2];
#pragma unroll
  for (int mi = 0; mi < 2; mi++)
#pragma unroll
    for (int kk = 0; kk < 2; kk++)
      qf[mi][kk] = *(const short8*)&Q[(size_t)(q0 + w * 32 + mi * 16 + lr) * HDIM + kk * 32 + lk];

  const short8 bones = {0x3F80, 0x3F80, 0x3F80, 0x3F80, 0x3F80, 0x3F80, 0x3F80, 0x3F80};

  f32x4 o[2][4];
  f32x4 ol[2];
#pragma unroll
  for (int mi = 0; mi < 2; mi++) {
    ol[mi] = (f32x4){0.f, 0.f, 0.f, 0.f};
#pragma unroll
    for (int nh = 0; nh < 4; nh++) o[mi][nh] = (f32x4){0.f, 0.f, 0.f, 0.f};
  }

  const int srow = t >> 3;        // 0..31
  const int scc  = (t & 7) * 8;   // elem offset within 64-elem row

  const int ntiles = 2 * qt + 2;
  for (int tkv = 0; tkv < ntiles; tkv++) {
    const int kv0 = tkv * KVB;
#pragma unroll
    for (int r = 0; r < 2; r++) {
      int row = srow + r * 32;
      short8 kv = *(const short8*)&Kg[(size_t)(kv0 + row) * HDIM + scc];
      *(short8*)&Ks[row * PSTR + scc] = kv;
      short8 vv = *(const short8*)&Vt[(size_t)row * SEQLEN + kv0 + scc];
      *(short8*)&Vs[row * PSTR + scc] = vv;
    }
    __syncthreads();

    const bool active = (kv0 <= q0 + w * 32 + 31);
    if (active) {
      short8 kf[4][2];
#pragma unroll
      for (int ni = 0; ni < 4; ni++)
#pragma unroll
        for (int kk = 0; kk < 2; kk++)
          kf[ni][kk] = *(const short8*)&Ks[(ni * 16 + lr) * PSTR + kk * 32 + lk];
      f32x4 s[2][4];
#pragma unroll
      for (int mi = 0; mi < 2; mi++)
#pragma unroll
        for (int ni = 0; ni < 4; ni++) {
          f32x4 a = (f32x4){0.f, 0.f, 0.f, 0.f};
#pragma unroll
          for (int kk = 0; kk < 2; kk++)
            a = __builtin_amdgcn_mfma_f32_16x16x32_bf16(qf[mi][kk], kf[ni][kk], a, 0, 0, 0);
          s[mi][ni] = a;
        }
      if (tkv >= ntiles - 2) {  // diagonal region: causal mask
#pragma unroll
        for (int mi = 0; mi < 2; mi++)
#pragma unroll
          for (int ni = 0; ni < 4; ni++)
#pragma unroll
            for (int j = 0; j < 4; j++) {
              int qq = q0 + w * 32 + mi * 16 + lkg * 4 + j;
              int kv = kv0 + ni * 16 + lr;
              if (kv > qq) s[mi][ni][j] = -1e30f;
            }
      }
      // sequential mi passes through the shared 16-row P buffer
#pragma unroll
      for (int mi = 0; mi < 2; mi++) {
#pragma unroll
        for (int ni = 0; ni < 4; ni++)
#pragma unroll
          for (int j = 0; j < 4; j++)
            ((short*)Ps[w])[(lkg * 4 + j) * PSTR + ni * 16 + lr] =
                trunc_bf16(__builtin_amdgcn_exp2f(s[mi][ni][j]));
#pragma unroll
        for (int kk = 0; kk < 2; kk++) {
          short8 pa = *(const short8*)&Ps[w][lr * PSTR + kk * 32 + lk];
          ol[mi] = __builtin_amdgcn_mfma_f32_16x16x32_bf16(pa, bones, ol[mi], 0, 0, 0);
#pragma unroll
          for (int nh = 0; nh < 4; nh++) {
            short8 vb = *(const short8*)&Vs[(nh * 16 + lr) * PSTR + kk * 32 + lk];
            o[mi][nh] = __builtin_amdgcn_mfma_f32_16x16x32_bf16(pa, vb, o[mi][nh], 0, 0, 0);
          }
        }
      }
    }
    __syncthreads();
  }

  const int b_ = bh >> 4, h_ = bh & 15;
#pragma unroll
  for (int mi = 0; mi < 2; mi++)
#pragma unroll
    for (int j = 0; j < 4; j++) {
      float inv = 1.0f / ol[mi][j];
      int qq = q0 + w * 32 + mi * 16 + lkg * 4 + j;
      size_t base = (((size_t)b_ * SEQLEN + qq) * NHEADS + h_) * HDIM;
#pragma unroll
      for (int nh = 0; nh < 4; nh++)
        ctx[base + nh * 16 + lr] = __float2bfloat16(o[mi][nh][j] * inv);
    }
}

// ---------------- confidence gate ----------------
__global__ __launch_bounds__(256) void pool_partial_k(
    const float* __restrict__ xo, float* __restrict__ part) {
  int blk = blockIdx.x;
  int b_ = blk >> 4, ch = blk & 15;
  int t = threadIdx.x;
  f32x4 acc = (f32x4){0.f, 0.f, 0.f, 0.f};
  const float* base = xo + ((size_t)b_ * SEQLEN + (size_t)ch * 128) * D_MODELC;
  for (int r = 0; r < 128; r++)
    acc += ((const f32x4*)(base + (size_t)r * D_MODELC))[t];
  ((f32x4*)(part + (size_t)blk * D_MODELC))[t] = acc;
}

__global__ __launch_bounds__(256) void conf_k(
    const float* __restrict__ part, const float* __restrict__ Wc,
    const float* __restrict__ bc, float* __restrict__ outc) {
  int t = threadIdx.x;
  __shared__ float red[4];
  float total = 0.f;
  for (int b_ = 0; b_ < BATCHN; b_++) {
    f32x4 sum = (f32x4){0.f, 0.f, 0.f, 0.f};
    for (int ch = 0; ch < 16; ch++)
      sum += ((const f32x4*)(part + (size_t)(b_ * 16 + ch) * D_MODELC))[t];
    f32x4 wv = ((const f32x4*)Wc)[t];
    float d = (sum[0] * wv[0] + sum[1] * wv[1] + sum[2] * wv[2] + sum[3] * wv[3]) * (1.0f / SEQLEN);
#pragma unroll
    for (int m = 1; m < 64; m <<= 1) d += __shfl_xor(d, m);
    int wq = t >> 6, l = t & 63;
    if (l == 0) red[wq] = d;
    __syncthreads();
    float z = red[0] + red[1] + red[2] + red[3] + bc[0];
    total += 1.0f / (1.0f + __expf(-z));
    __syncthreads();
  }
  if (t == 0) outc[0] = total * (1.0f / BATCHN);
}

// ---------------- launch ----------------
extern "C" void kernel_launch(void* const* d_in, const int* in_sizes, int n_in,
                              void* d_out, int out_size, void* d_ws, size_t ws_size,
                              hipStream_t stream) {
  const float* x    = (const float*)d_in[0];
  const float* Wq   = (const float*)d_in[1];
  const float* Wk   = (const float*)d_in[2];
  const float* Wv   = (const float*)d_in[3];
  const float* Wo   = (const float*)d_in[4];
  const float* ln1g = (const float*)d_in[5];
  const float* ln1b = (const float*)d_in[6];
  const float* ln2g = (const float*)d_in[7];
  const float* ln2b = (const float*)d_in[8];
  const float* W1   = (const float*)d_in[9];
  const float* b1   = (const float*)d_in[10];
  const float* W2   = (const float*)d_in[11];
  const float* b2   = (const float*)d_in[12];
  const float* Wc   = (const float*)d_in[13];
  const float* bc   = (const float*)d_in[14];

  char* ws = (char*)d_ws;
  const size_t MB = 1024 * 1024;
  bf16* qkv   = (bf16*)(ws);                    // q,k [bh][S][64]; vT [bh][64][S]
  bf16* ctx   = (bf16*)(ws + 48 * MB);
  bf16* ff1   = (bf16*)(ws);                    // reuse qkv region (64MB)
  bf16* h     = (bf16*)(ws + 64 * MB);          // 16MB (h, then h2)
  bf16* WqkvT = (bf16*)(ws + 80 * MB);          // 6MB: [3072][1024]
  bf16* WoT   = (bf16*)(ws + 86 * MB);          // 2MB
  bf16* W1T   = (bf16*)(ws + 88 * MB);          // 8MB: [4096][1024]
  bf16* W2T   = (bf16*)(ws + 96 * MB);          // 8MB: [1024][4096]
  float* part = (float*)(ws + 104 * MB);        // 256KB

  float* xout = (float*)d_out;
  dim3 blk(256);

  const float SCL2 = 0.125f * 1.44269504f;  // fold score-scale * log2(e) into Wq

  // weights -> bf16, transposed to [N][K]
  transpose_bf16_k<<<dim3(32, 32), blk, 0, stream>>>(Wq, WqkvT, 1024, 1024, SCL2);
  transpose_bf16_k<<<dim3(32, 32), blk, 0, stream>>>(Wk, WqkvT + 1024 * 1024, 1024, 1024, 1.0f);
  transpose_bf16_k<<<dim3(32, 32), blk, 0, stream>>>(Wv, WqkvT + 2 * 1024 * 1024, 1024, 1024, 1.0f);
  transpose_bf16_k<<<dim3(32, 32), blk, 0, stream>>>(Wo, WoT, 1024, 1024, 1.0f);
  transpose_bf16_k<<<dim3(128, 32), blk, 0, stream>>>(W1, W1T, 1024, 4096, 1.0f);
  transpose_bf16_k<<<dim3(32, 128), blk, 0, stream>>>(W2, W2T, 4096, 1024, 1.0f);

  // LN1 -> h (bf16)
  ln_bf16_k<<<MTOT, blk, 0, stream>>>(x, ln1g, ln1b, h);
  // QKV: -> q,k [B,H,S,64]; v transposed [B,H,64,S]
  gemm_nt<EPI_QKV><<<dim3(3072 / BN, MTOT / BM), blk, 0, stream>>>(
      h, WqkvT, MTOT, 3072, 1024, nullptr, nullptr, nullptr, qkv);
  // attention -> ctx [M][1024]
  attn_k<<<dim3((SEQLEN / QB2) * 64), blk, 0, stream>>>(
      qkv, qkv + (size_t)MTOT * D_MODELC, qkv + 2 * (size_t)MTOT * D_MODELC, ctx);
  // x1 = x + ctx @ Wo  (fp32, into d_out)
  gemm_nt<EPI_RESID><<<dim3(1024 / BN, MTOT / BM), blk, 0, stream>>>(
      ctx, WoT, MTOT, 1024, 1024, nullptr, x, xout, nullptr);
  // LN2 -> h2 (bf16)
  ln_bf16_k<<<MTOT, blk, 0, stream>>>(xout, ln2g, ln2b, h);
  // ff1 = relu(h2 @ W1 + b1) (bf16)
  gemm_nt<EPI_BIAS_RELU><<<dim3(4096 / BN, MTOT / BM), blk, 0, stream>>>(
      h, W1T, MTOT, 4096, 1024, b1, nullptr, nullptr, ff1);
  // x_out = x1 + ff1 @ W2 + b2 (fp32, in-place in d_out)
  gemm_nt<EPI_BIAS_RESID><<<dim3(1024 / BN, MTOT / BM), blk, 0, stream>>>(
      ff1, W2T, MTOT, 1024, 4096, b2, xout, xout, nullptr);
  // confidence gate
  pool_partial_k<<<64, blk, 0, stream>>>(xout, part);
  conf_k<<<1, blk, 0, stream>>>(part, Wc, bc, xout + (size_t)MTOT * D_MODELC);
}

// Round 18
// 394.812 us; speedup vs baseline: 1.2313x; 1.0167x over previous
//
#include <hip/hip_runtime.h>
#include <hip/hip_bf16.h>

typedef __hip_bfloat16 bf16;
typedef __attribute__((ext_vector_type(8))) short short8;
typedef __attribute__((ext_vector_type(4))) float f32x4;

#define D_MODELC 1024
#define D_FFC    4096
#define NHEADS   16
#define HDIM     64
#define SEQLEN   2048
#define BATCHN   4
#define MTOT     (BATCHN * SEQLEN)   // 8192

// ---------------- async global->LDS (16B per lane) ----------------
__device__ __forceinline__ void async16(void* lds, const void* g) {
  __builtin_amdgcn_global_load_lds(
      (const __attribute__((address_space(1))) unsigned int*)g,
      (__attribute__((address_space(3))) unsigned int*)lds, 16, 0, 0);
}

// ---------------- batched 1024x1024 weight transpose-convert ----------------
// z selects among 4 weights {Wq,Wk,Wv,Wo} -> dst + z*1M elems (WoT contiguous
// after WqkvT in ws). scale applied only to z==0 (Wq exp2-domain fold).
__global__ __launch_bounds__(256) void transpose4_bf16_k(
    const float* __restrict__ w0, const float* __restrict__ w1,
    const float* __restrict__ w2, const float* __restrict__ w3,
    bf16* __restrict__ dst, float scale0) {
  __shared__ float tile[32][33];
  const float* srcs[4] = {w0, w1, w2, w3};
  const float* src = srcs[blockIdx.z];
  bf16* d = dst + (size_t)blockIdx.z * 1024 * 1024;
  float scale = (blockIdx.z == 0) ? scale0 : 1.0f;
  int tx = threadIdx.x & 31, ty = threadIdx.x >> 5;
  int r0 = blockIdx.y * 32, c0 = blockIdx.x * 32;
#pragma unroll
  for (int i = 0; i < 4; i++) {
    int r = ty + i * 8;
    tile[r][tx] = src[(size_t)(r0 + r) * 1024 + c0 + tx];
  }
  __syncthreads();
#pragma unroll
  for (int i = 0; i < 4; i++) {
    int c = ty + i * 8;
    d[(size_t)(c0 + c) * 1024 + r0 + tx] = __float2bfloat16(tile[tx][c] * scale);
  }
}

// ---------------- generic transpose-convert: src[R][C] f32 -> dst[C][R] bf16 ----------------
__global__ __launch_bounds__(256) void transpose_bf16_k(
    const float* __restrict__ src, bf16* __restrict__ dst, int R, int C, float scale) {
  __shared__ float tile[32][33];
  int tx = threadIdx.x & 31, ty = threadIdx.x >> 5;
  int r0 = blockIdx.y * 32, c0 = blockIdx.x * 32;
#pragma unroll
  for (int i = 0; i < 4; i++) {
    int r = ty + i * 8;
    tile[r][tx] = src[(size_t)(r0 + r) * C + c0 + tx];
  }
  __syncthreads();
#pragma unroll
  for (int i = 0; i < 4; i++) {
    int c = ty + i * 8;
    dst[(size_t)(c0 + c) * R + r0 + tx] = __float2bfloat16(tile[tx][c] * scale);
  }
}

// ---------------- LayerNorm f32 row (1024) -> bf16 ----------------
__global__ __launch_bounds__(256) void ln_bf16_k(
    const float* __restrict__ x, const float* __restrict__ g,
    const float* __restrict__ b, bf16* __restrict__ out) {
  int row = blockIdx.x;
  int t = threadIdx.x;
  f32x4 v = ((const f32x4*)(x + (size_t)row * D_MODELC))[t];
  float s = v[0] + v[1] + v[2] + v[3];
  float ss = v[0] * v[0] + v[1] * v[1] + v[2] * v[2] + v[3] * v[3];
#pragma unroll
  for (int m = 1; m < 64; m <<= 1) {
    s += __shfl_xor(s, m);
    ss += __shfl_xor(ss, m);
  }
  __shared__ float red[8];
  int w = t >> 6, l = t & 63;
  if (l == 0) { red[w] = s; red[4 + w] = ss; }
  __syncthreads();
  s = red[0] + red[1] + red[2] + red[3];
  ss = red[4] + red[5] + red[6] + red[7];
  float mean = s * (1.0f / D_MODELC);
  float var = ss * (1.0f / D_MODELC) - mean * mean;
  float rs = rsqrtf(var + 1e-5f);
  f32x4 gv = ((const f32x4*)g)[t];
  f32x4 bv = ((const f32x4*)b)[t];
  unsigned short u[4];
#pragma unroll
  for (int j = 0; j < 4; j++) {
    float o = (v[j] - mean) * rs * gv[j] + bv[j];
    u[j] = __bfloat16_as_ushort(__float2bfloat16(o));
  }
  unsigned int lo = (unsigned int)u[0] | ((unsigned int)u[1] << 16);
  unsigned int hi = (unsigned int)u[2] | ((unsigned int)u[3] << 16);
  ((uint2*)(out + (size_t)row * D_MODELC))[t] = make_uint2(lo, hi);
}

enum { EPI_QKV = 0, EPI_RESID = 1, EPI_BIAS_RELU = 2, EPI_BIAS_RESID = 3 };

// ---------------- epilogue element write ----------------
template <int EPI>
__device__ __forceinline__ void epi_write(
    int gm, int gn, float v, int N,
    const float* __restrict__ bias, const float* __restrict__ resid,
    float* __restrict__ outF, bf16* __restrict__ outB) {
  if constexpr (EPI == EPI_QKV) {
    int sel = gn >> 10, d = gn & 1023;
    int b_ = gm >> 11, s_ = gm & 2047;
    int h2 = d >> 6, dd = d & 63;
    size_t bh = (size_t)b_ * NHEADS + h2;
    size_t dst;
    if (sel < 2) {
      dst = (size_t)sel * ((size_t)MTOT * D_MODELC) + (bh * SEQLEN + s_) * HDIM + dd;
    } else {
      // V stored TRANSPOSED: [bh][d][S]
      dst = 2 * ((size_t)MTOT * D_MODELC) + (bh * HDIM + dd) * SEQLEN + s_;
    }
    outB[dst] = __float2bfloat16(v);
  } else if constexpr (EPI == EPI_RESID) {
    size_t idx = (size_t)gm * N + gn;
    outF[idx] = resid[idx] + v;
  } else if constexpr (EPI == EPI_BIAS_RELU) {
    float z = v + bias[gn];
    outB[(size_t)gm * N + gn] = __float2bfloat16(z > 0.f ? z : 0.f);
  } else {
    size_t idx = (size_t)gm * N + gn;
    outF[idx] = resid[idx] + v + bias[gn];
  }
}

// ---------------- 128x128 bf16 NT GEMM (proven m97-structure) ----------------
#define BM 128
#define BN 128
#define BKK 64

template <int EPI>
__global__ __launch_bounds__(256) void gemm_nt(
    const bf16* __restrict__ A, const bf16* __restrict__ BT, int M, int N, int K,
    const float* __restrict__ bias, const float* __restrict__ resid,
    float* __restrict__ outF, bf16* __restrict__ outB) {
  __shared__ bf16 As[BM * BKK];
  __shared__ bf16 Bs[BN * BKK];
  const int t = threadIdx.x;
  const int l = t & 63;
  const int w = t >> 6;
  const int wm = w >> 1, wn = w & 1;

  int nwg = gridDim.x * gridDim.y;
  int bid = blockIdx.y * gridDim.x + blockIdx.x;
  if ((nwg & 7) == 0) {
    int q8 = nwg >> 3;
    bid = (bid & 7) * q8 + (bid >> 3);
  }
  const int bx = bid % gridDim.x, by = bid / gridDim.x;
  const int m0 = by * BM, n0 = bx * BN;
  const int lr = l & 15, lkg = l >> 4;

  f32x4 acc[4][4];
#pragma unroll
  for (int i = 0; i < 4; i++)
#pragma unroll
    for (int j = 0; j < 4; j++) acc[i][j] = (f32x4){0.f, 0.f, 0.f, 0.f};

  const char* Abase = (const char*)(A + (size_t)m0 * K);
  const char* Bbase = (const char*)(BT + (size_t)n0 * K);

  for (int k0 = 0; k0 < K; k0 += BKK) {
#pragma unroll
    for (int c = 0; c < 4; c++) {
      int off = (c * 256 + t) * 16;
      int r = off >> 7;
      int sg = ((off >> 4) & 7) ^ (r & 7);
      async16((char*)As + off, Abase + ((size_t)r * K + k0) * 2 + sg * 16);
      async16((char*)Bs + off, Bbase + ((size_t)r * K + k0) * 2 + sg * 16);
    }
    __syncthreads();
    short8 a[2][4], b[2][4];
#pragma unroll
    for (int kk = 0; kk < 2; kk++) {
#pragma unroll
      for (int mi = 0; mi < 4; mi++) {
        int row = wm * 64 + mi * 16 + lr;
        int sl = (kk * 4 + lkg) ^ (row & 7);
        a[kk][mi] = *(const short8*)((const char*)As + row * 128 + sl * 16);
      }
#pragma unroll
      for (int ni = 0; ni < 4; ni++) {
        int row = wn * 64 + ni * 16 + lr;
        int sl = (kk * 4 + lkg) ^ (row & 7);
        b[kk][ni] = *(const short8*)((const char*)Bs + row * 128 + sl * 16);
      }
    }
#pragma unroll
    for (int kk = 0; kk < 2; kk++)
#pragma unroll
      for (int mi = 0; mi < 4; mi++)
#pragma unroll
        for (int ni = 0; ni < 4; ni++)
          acc[mi][ni] = __builtin_amdgcn_mfma_f32_16x16x32_bf16(a[kk][mi], b[kk][ni], acc[mi][ni], 0, 0, 0);
    __syncthreads();
  }

#pragma unroll
  for (int mi = 0; mi < 4; mi++)
#pragma unroll
    for (int ni = 0; ni < 4; ni++)
#pragma unroll
      for (int j = 0; j < 4; j++) {
        int gm = m0 + wm * 64 + mi * 16 + lkg * 4 + j;
        int gn = n0 + wn * 64 + ni * 16 + lr;
        epi_write<EPI>(gm, gn, acc[mi][ni][j], N, bias, resid, outF, outB);
      }
}

// ---------------- causal flash attention (no-max softmax, seq-mi, lean VALU) ----------------
#define KVB 64
#define QB2 128
#define PSTR 76

__device__ __forceinline__ short trunc_bf16(float x) {
  return (short)(__float_as_uint(x) >> 16);
}

__global__ __launch_bounds__(256) void attn_k(
    const bf16* __restrict__ qg, const bf16* __restrict__ kg,
    const bf16* __restrict__ vtg, bf16* __restrict__ ctx) {
  const int bid = blockIdx.x;
  const int qt = (SEQLEN / QB2 - 1) - (bid >> 6);  // 15..0, long blocks first
  const int bh = bid & 63;
  const int q0 = qt * QB2;
  const int t = threadIdx.x, w = t >> 6, l = t & 63;
  const int lr = l & 15, lkg = l >> 4, lk = lkg * 8;

  const bf16* Q  = qg  + (size_t)bh * SEQLEN * HDIM;
  const bf16* Kg = kg  + (size_t)bh * SEQLEN * HDIM;
  const bf16* Vt = vtg + (size_t)bh * HDIM * SEQLEN;

  __shared__ bf16 Ks[KVB * PSTR];
  __shared__ bf16 Vs[HDIM * PSTR];
  __shared__ bf16 Ps[4][16 * PSTR];   // 16 rows per wave, shared by mi passes

  short8 qf[2][2];
#pragma unroll
  for (int mi = 0; mi < 2; mi++)
#pragma unroll
    for (int kk = 0; kk < 2; kk++)
      qf[mi][kk] = *(const short8*)&Q[(size_t)(q0 + w * 32 + mi * 16 + lr) * HDIM + kk * 32 + lk];

  const short8 bones = {0x3F80, 0x3F80, 0x3F80, 0x3F80, 0x3F80, 0x3F80, 0x3F80, 0x3F80};

  f32x4 o[2][4];
  f32x4 ol[2];
#pragma unroll
  for (int mi = 0; mi < 2; mi++) {
    ol[mi] = (f32x4){0.f, 0.f, 0.f, 0.f};
#pragma unroll
    for (int nh = 0; nh < 4; nh++) o[mi][nh] = (f32x4){0.f, 0.f, 0.f, 0.f};
  }

  const int srow = t >> 3;        // 0..31
  const int scc  = (t & 7) * 8;   // elem offset within 64-elem row

  const int ntiles = 2 * qt + 2;
  for (int tkv = 0; tkv < ntiles; tkv++) {
    const int kv0 = tkv * KVB;
#pragma unroll
    for (int r = 0; r < 2; r++) {
      int row = srow + r * 32;
      short8 kv = *(const short8*)&Kg[(size_t)(kv0 + row) * HDIM + scc];
      *(short8*)&Ks[row * PSTR + scc] = kv;
      short8 vv = *(const short8*)&Vt[(size_t)row * SEQLEN + kv0 + scc];
      *(short8*)&Vs[row * PSTR + scc] = vv;
    }
    __syncthreads();

    const bool active = (kv0 <= q0 + w * 32 + 31);
    if (active) {
      short8 kf[4][2];
#pragma unroll
      for (int ni = 0; ni < 4; ni++)
#pragma unroll
        for (int kk = 0; kk < 2; kk++)
          kf[ni][kk] = *(const short8*)&Ks[(ni * 16 + lr) * PSTR + kk * 32 + lk];
      f32x4 s[2][4];
#pragma unroll
      for (int mi = 0; mi < 2; mi++)
#pragma unroll
        for (int ni = 0; ni < 4; ni++) {
          f32x4 a = (f32x4){0.f, 0.f, 0.f, 0.f};
#pragma unroll
          for (int kk = 0; kk < 2; kk++)
            a = __builtin_amdgcn_mfma_f32_16x16x32_bf16(qf[mi][kk], kf[ni][kk], a, 0, 0, 0);
          s[mi][ni] = a;
        }
      if (tkv >= ntiles - 2) {  // diagonal region: causal mask
#pragma unroll
        for (int mi = 0; mi < 2; mi++)
#pragma unroll
          for (int ni = 0; ni < 4; ni++)
#pragma unroll
            for (int j = 0; j < 4; j++) {
              int qq = q0 + w * 32 + mi * 16 + lkg * 4 + j;
              int kv = kv0 + ni * 16 + lr;
              if (kv > qq) s[mi][ni][j] = -1e30f;
            }
      }
      // sequential mi passes through the shared 16-row P buffer
#pragma unroll
      for (int mi = 0; mi < 2; mi++) {
#pragma unroll
        for (int ni = 0; ni < 4; ni++)
#pragma unroll
          for (int j = 0; j < 4; j++)
            ((short*)Ps[w])[(lkg * 4 + j) * PSTR + ni * 16 + lr] =
                trunc_bf16(__builtin_amdgcn_exp2f(s[mi][ni][j]));
#pragma unroll
        for (int kk = 0; kk < 2; kk++) {
          short8 pa = *(const short8*)&Ps[w][lr * PSTR + kk * 32 + lk];
          ol[mi] = __builtin_amdgcn_mfma_f32_16x16x32_bf16(pa, bones, ol[mi], 0, 0, 0);
#pragma unroll
          for (int nh = 0; nh < 4; nh++) {
            short8 vb = *(const short8*)&Vs[(nh * 16 + lr) * PSTR + kk * 32 + lk];
            o[mi][nh] = __builtin_amdgcn_mfma_f32_16x16x32_bf16(pa, vb, o[mi][nh], 0, 0, 0);
          }
        }
      }
    }
    __syncthreads();
  }

  const int b_ = bh >> 4, h_ = bh & 15;
#pragma unroll
  for (int mi = 0; mi < 2; mi++)
#pragma unroll
    for (int j = 0; j < 4; j++) {
      float inv = 1.0f / ol[mi][j];
      int qq = q0 + w * 32 + mi * 16 + lkg * 4 + j;
      size_t base = (((size_t)b_ * SEQLEN + qq) * NHEADS + h_) * HDIM;
#pragma unroll
      for (int nh = 0; nh < 4; nh++)
        ctx[base + nh * 16 + lr] = __float2bfloat16(o[mi][nh][j] * inv);
    }
}

// ---------------- confidence gate ----------------
__global__ __launch_bounds__(256) void pool_partial_k(
    const float* __restrict__ xo, float* __restrict__ part) {
  int blk = blockIdx.x;
  int b_ = blk >> 4, ch = blk & 15;
  int t = threadIdx.x;
  f32x4 acc = (f32x4){0.f, 0.f, 0.f, 0.f};
  const float* base = xo + ((size_t)b_ * SEQLEN + (size_t)ch * 128) * D_MODELC;
  for (int r = 0; r < 128; r++)
    acc += ((const f32x4*)(base + (size_t)r * D_MODELC))[t];
  ((f32x4*)(part + (size_t)blk * D_MODELC))[t] = acc;
}

__global__ __launch_bounds__(256) void conf_k(
    const float* __restrict__ part, const float* __restrict__ Wc,
    const float* __restrict__ bc, float* __restrict__ outc) {
  int t = threadIdx.x;
  __shared__ float red[4];
  float total = 0.f;
  for (int b_ = 0; b_ < BATCHN; b_++) {
    f32x4 sum = (f32x4){0.f, 0.f, 0.f, 0.f};
    for (int ch = 0; ch < 16; ch++)
      sum += ((const f32x4*)(part + (size_t)(b_ * 16 + ch) * D_MODELC))[t];
    f32x4 wv = ((const f32x4*)Wc)[t];
    float d = (sum[0] * wv[0] + sum[1] * wv[1] + sum[2] * wv[2] + sum[3] * wv[3]) * (1.0f / SEQLEN);
#pragma unroll
    for (int m = 1; m < 64; m <<= 1) d += __shfl_xor(d, m);
    int wq = t >> 6, l = t & 63;
    if (l == 0) red[wq] = d;
    __syncthreads();
    float z = red[0] + red[1] + red[2] + red[3] + bc[0];
    total += 1.0f / (1.0f + __expf(-z));
    __syncthreads();
  }
  if (t == 0) outc[0] = total * (1.0f / BATCHN);
}

// ---------------- launch ----------------
extern "C" void kernel_launch(void* const* d_in, const int* in_sizes, int n_in,
                              void* d_out, int out_size, void* d_ws, size_t ws_size,
                              hipStream_t stream) {
  const float* x    = (const float*)d_in[0];
  const float* Wq   = (const float*)d_in[1];
  const float* Wk   = (const float*)d_in[2];
  const float* Wv   = (const float*)d_in[3];
  const float* Wo   = (const float*)d_in[4];
  const float* ln1g = (const float*)d_in[5];
  const float* ln1b = (const float*)d_in[6];
  const float* ln2g = (const float*)d_in[7];
  const float* ln2b = (const float*)d_in[8];
  const float* W1   = (const float*)d_in[9];
  const float* b1   = (const float*)d_in[10];
  const float* W2   = (const float*)d_in[11];
  const float* b2   = (const float*)d_in[12];
  const float* Wc   = (const float*)d_in[13];
  const float* bc   = (const float*)d_in[14];

  char* ws = (char*)d_ws;
  const size_t MB = 1024 * 1024;
  bf16* qkv   = (bf16*)(ws);                    // q,k [bh][S][64]; vT [bh][64][S]
  bf16* ctx   = (bf16*)(ws + 48 * MB);
  bf16* ff1   = (bf16*)(ws);                    // reuse qkv region (64MB)
  bf16* h     = (bf16*)(ws + 64 * MB);          // 16MB (h, then h2)
  bf16* WqkvT = (bf16*)(ws + 80 * MB);          // 6MB: [3072][1024]; WoT follows
  bf16* WoT   = (bf16*)(ws + 86 * MB);          // 2MB (= WqkvT + 3M elems)
  bf16* W1T   = (bf16*)(ws + 88 * MB);          // 8MB: [4096][1024]
  bf16* W2T   = (bf16*)(ws + 96 * MB);          // 8MB: [1024][4096]
  float* part = (float*)(ws + 104 * MB);        // 256KB

  float* xout = (float*)d_out;
  dim3 blk(256);

  const float SCL2 = 0.125f * 1.44269504f;  // fold score-scale * log2(e) into Wq

  // weights -> bf16, transposed to [N][K]: one batched launch for the 4 1024^2
  // weights (z=0..3 -> WqkvT+z*1M; z=3 lands on WoT), plus W1T/W2T.
  transpose4_bf16_k<<<dim3(32, 32, 4), blk, 0, stream>>>(Wq, Wk, Wv, Wo, WqkvT, SCL2);
  transpose_bf16_k<<<dim3(128, 32), blk, 0, stream>>>(W1, W1T, 1024, 4096, 1.0f);
  transpose_bf16_k<<<dim3(32, 128), blk, 0, stream>>>(W2, W2T, 4096, 1024, 1.0f);

  // LN1 -> h (bf16)
  ln_bf16_k<<<MTOT, blk, 0, stream>>>(x, ln1g, ln1b, h);
  // QKV: -> q,k [B,H,S,64]; v transposed [B,H,64,S]
  gemm_nt<EPI_QKV><<<dim3(3072 / BN, MTOT / BM), blk, 0, stream>>>(
      h, WqkvT, MTOT, 3072, 1024, nullptr, nullptr, nullptr, qkv);
  // attention -> ctx [M][1024]
  attn_k<<<dim3((SEQLEN / QB2) * 64), blk, 0, stream>>>(
      qkv, qkv + (size_t)MTOT * D_MODELC, qkv + 2 * (size_t)MTOT * D_MODELC, ctx);
  // x1 = x + ctx @ Wo  (fp32, into d_out)
  gemm_nt<EPI_RESID><<<dim3(1024 / BN, MTOT / BM), blk, 0, stream>>>(
      ctx, WoT, MTOT, 1024, 1024, nullptr, x, xout, nullptr);
  // LN2 -> h2 (bf16)
  ln_bf16_k<<<MTOT, blk, 0, stream>>>(xout, ln2g, ln2b, h);
  // ff1 = relu(h2 @ W1 + b1) (bf16)
  gemm_nt<EPI_BIAS_RELU><<<dim3(4096 / BN, MTOT / BM), blk, 0, stream>>>(
      h, W1T, MTOT, 4096, 1024, b1, nullptr, nullptr, ff1);
  // x_out = x1 + ff1 @ W2 + b2 (fp32, in-place in d_out)
  gemm_nt<EPI_BIAS_RESID><<<dim3(1024 / BN, MTOT / BM), blk, 0, stream>>>(
      ff1, W2T, MTOT, 1024, 4096, b2, xout, xout, nullptr);
  // confidence gate
  pool_partial_k<<<64, blk, 0, stream>>>(xout, part);
  conf_k<<<1, blk, 0, stream>>>(part, Wc, bc, xout + (size_t)MTOT * D_MODELC);
}